// Round 1
// baseline (185.660 us; speedup 1.0000x reference)
//
#include <hip/hip_runtime.h>
#include <hip/hip_bf16.h>
#include <math.h>

#define NSRC 50000
#define NTGT 50000
#define NTOT 100000
#define NEDGE 800000
#define DIM 128
#define WPAD 136        // Bs LDS row pitch (ushorts): aggregate-uniform bank use on b128 reads

#define NBUCK 196       // coarse buckets of 256 targets (49999>>8 = 195)
#define BCAP 6144       // max edges per bucket (mean 4096, +32 sigma)
#define EPT 8           // edges per thread in partition path
#define EPB2 2048       // edges per partition block (256 thr * 8)
#define PBLK2 391       // ceil(800000 / 2048)
#define GEMM_GRID 1563  // ceil(100000 / 64)
#define FGRID (PBLK2 + GEMM_GRID)

typedef __attribute__((ext_vector_type(8))) short short8;
typedef __attribute__((ext_vector_type(4))) float float4v;

union U8 { short8 s; uint4 u; };

__device__ __forceinline__ float bf2f(unsigned us) {
    return __uint_as_float(us << 16);
}
// packed RNE f32x2 -> bf16x2 (v_cvt_pk_bf16_f32)
__device__ __forceinline__ unsigned pkbf(float lo, float hi) {
    __hip_bfloat162 b = __float22bfloat162_rn(make_float2(lo, hi));
    return *(unsigned*)&b;
}

// ---------------- fused: edge partition (blocks 0..390) + GEMM (rest) -----
// partition: packed entry row(16b) | c_local(8b), run-reserved via global bcnt
// gemm: h = x @ W via bf16 MFMA (operand-swapped); W transposed to bf16 in
//       LDS inline (no Wt buffer, no prep kernel)
__global__ __launch_bounds__(256) void k_front(const int* __restrict__ row,
                                               const int* __restrict__ col,
                                               int* __restrict__ bcnt,
                                               unsigned* __restrict__ part,
                                               const float* __restrict__ xsrc,
                                               const float* __restrict__ xtgt,
                                               const float* __restrict__ W,
                                               unsigned short* __restrict__ h,
                                               float* __restrict__ out) {
    __shared__ union SM {
        struct { int hist[NBUCK]; int runbase[NBUCK]; int cur[NBUCK]; } p;
        unsigned short Bs[128 * WPAD];  // 34 KB -> 4 blocks/CU
    } sm;

    const int tid = threadIdx.x;

    if (blockIdx.x < PBLK2) {
        // ---------------- partition path ----------------
        if (tid < NBUCK) sm.p.hist[tid] = 0;
        __syncthreads();

        int e0 = blockIdx.x * EPB2 + tid * EPT;
        bool valid = (e0 + EPT <= NEDGE);  // NEDGE%8==0 -> all-or-nothing
        int c[EPT], r[EPT];
        if (valid) {
            *(int4*)&c[0] = *(const int4*)(col + e0);
            *(int4*)&c[4] = *(const int4*)(col + e0 + 4);
            *(int4*)&r[0] = *(const int4*)(row + e0);
            *(int4*)&r[4] = *(const int4*)(row + e0 + 4);
#pragma unroll
            for (int i = 0; i < EPT; ++i) atomicAdd(&sm.p.hist[c[i] >> 8], 1);
        }
        __syncthreads();
        if (tid < NBUCK) {
            sm.p.runbase[tid] = atomicAdd(&bcnt[tid], sm.p.hist[tid]);  // reserve run
            sm.p.cur[tid] = 0;
        }
        __syncthreads();
        if (valid) {
#pragma unroll
            for (int i = 0; i < EPT; ++i) {
                int q = c[i] >> 8;
                int pos = sm.p.runbase[q] + atomicAdd(&sm.p.cur[q], 1);
                part[q * BCAP + pos] = (unsigned)r[i] | ((unsigned)(c[i] & 255) << 16);
            }
        }
        return;
    }

    // ---------------- gemm path ----------------
    const int gb = blockIdx.x - PBLK2;

    // W (fp32 row-major) -> Bs[n*WPAD+k] = bf16(W[k][n]); coalesced row-pair
    // loads, packed b32 LDS writes, j rotated by lane to spread banks (4-way)
#pragma unroll 2
    for (int rr = 0; rr < 8; ++rr) {
        int task = rr * 256 + tid;  // 2048 tasks = 64 row-pairs x 32 col-groups
        int kp = task >> 5;         // row pair: rows 2kp, 2kp+1
        int g = task & 31;          // col group: cols 4g..4g+3
        const float* w0 = W + (2 * kp) * DIM + g * 4;
        float4 f0 = *(const float4*)w0;
        float4 f1 = *(const float4*)(w0 + DIM);
        const float* f0p = (const float*)&f0;
        const float* f1p = (const float*)&f1;
#pragma unroll
        for (int jj = 0; jj < 4; ++jj) {
            int j = (jj + g) & 3;
            *(unsigned*)&sm.Bs[(g * 4 + j) * WPAD + 2 * kp] = pkbf(f0p[j], f1p[j]);
        }
    }

    const int wave = tid >> 6, lane = tid & 63;
    const int nl = lane & 15, quad = lane >> 4;

    // prefetch x fragments (issued before the Bs barrier)
    int node = gb * 64 + wave * 16 + nl;
    int mc = (node < NTOT) ? node : (NTOT - 1);  // clamp tail loads
    const float* xrow = (mc < NSRC) ? (xsrc + (size_t)mc * DIM)
                                    : (xtgt + (size_t)(mc - NSRC) * DIM);
    float4 a[8];
#pragma unroll
    for (int s = 0; s < 4; ++s) {
        a[2 * s]     = *(const float4*)(xrow + s * 32 + quad * 8);
        a[2 * s + 1] = *(const float4*)(xrow + s * 32 + quad * 8 + 4);
    }
    __syncthreads();  // Bs ready

    float4v acc[8];
#pragma unroll
    for (int t = 0; t < 8; ++t) acc[t] = (float4v){0.f, 0.f, 0.f, 0.f};

#pragma unroll
    for (int s = 0; s < 4; ++s) {
        U8 af;
        af.u.x = pkbf(a[2 * s].x, a[2 * s].y);
        af.u.y = pkbf(a[2 * s].z, a[2 * s].w);
        af.u.z = pkbf(a[2 * s + 1].x, a[2 * s + 1].y);
        af.u.w = pkbf(a[2 * s + 1].z, a[2 * s + 1].w);
#pragma unroll
        for (int t = 0; t < 8; ++t) {
            short8 bf = *(const short8*)&sm.Bs[(t * 16 + nl) * WPAD + s * 32 + quad * 8];
            // A = W^T tile (features as M), B = x tile (nodes as N)
            acc[t] = __builtin_amdgcn_mfma_f32_16x16x32_bf16(bf, af.s, acc[t], 0, 0, 0);
        }
    }

    if (node < NTOT) {
        // lane owns node `node`, features t*16 + quad*4 .. +3
        unsigned short* hp = h + (size_t)node * DIM + quad * 4;
        float* op = out + (size_t)node * DIM + quad * 4;
        bool isrc = (node < NSRC);
#pragma unroll
        for (int t = 0; t < 8; ++t) {
            uint2 p;
            p.x = pkbf(acc[t][0], acc[t][1]);
            p.y = pkbf(acc[t][2], acc[t][3]);
            *(uint2*)(hp + t * 16) = p;
            if (isrc) {  // source nodes: deg=1 -> out = relu(h), fp32 acc
                float4 o;
                o.x = fmaxf(acc[t][0], 0.f);
                o.y = fmaxf(acc[t][1], 0.f);
                o.z = fmaxf(acc[t][2], 0.f);
                o.w = fmaxf(acc[t][3], 0.f);
                *(float4*)(op + t * 16) = o;
            }
        }
    }
}

// ---------------- per-bucket local sort -> csr (ushort) + tstart/tcnt -----
__global__ __launch_bounds__(1024) void k_bucket(const int* __restrict__ bcnt,
                                                 const unsigned* __restrict__ part,
                                                 unsigned short* __restrict__ csr,
                                                 int* __restrict__ tstart,
                                                 int* __restrict__ tcnt) {
    __shared__ unsigned ebuf[BCAP];
    __shared__ unsigned short srt[BCAP];
    __shared__ int hist[256], bufA[256], bufB[256], cur[256];

    int q = blockIdx.x, tid = threadIdx.x;
    int n = bcnt[q];
    int base = q * BCAP;

    if (tid < 256) hist[tid] = 0;
    __syncthreads();
    for (int i = tid; i < n; i += 1024) {
        unsigned p = part[base + i];
        ebuf[i] = p;
        atomicAdd(&hist[p >> 16], 1);
    }
    __syncthreads();

    // exclusive scan of hist[256] (first 256 threads, double-buffered)
    if (tid < 256) bufA[tid] = hist[tid];
    int* src = bufA; int* dst = bufB;
    for (int d = 1; d < 256; d <<= 1) {
        __syncthreads();
        if (tid < 256) dst[tid] = src[tid] + ((tid >= d) ? src[tid - d] : 0);
        int* t = src; src = dst; dst = t;
    }
    __syncthreads();
    if (tid < 256) {
        int excl = src[tid] - hist[tid];
        cur[tid] = excl;
        int c = q * 256 + tid;
        if (c < NTGT) {
            tstart[c] = base + excl;
            tcnt[c] = hist[tid];
        }
    }
    __syncthreads();

    for (int i = tid; i < n; i += 1024) {
        unsigned p = ebuf[i];
        int pos = atomicAdd(&cur[p >> 16], 1);
        srt[pos] = (unsigned short)(p & 0xffffu);
    }
    __syncthreads();
    // coalesced writeout, 2 ushorts per store (base is 4B-aligned: BCAP even)
    int m = (n + 1) >> 1;
    unsigned* dst32 = (unsigned*)(csr + base);
    for (int i = tid; i < m; i += 1024) dst32[i] = ((unsigned*)srt)[i];
}

// ---------------- per-target gather-reduce (bf16 h, 4 edges/iter) ---------
// one wave per target; quarter-wave (16 lanes) per edge, uint4 (8 bf16)/lane
__global__ __launch_bounds__(256) void k_agg(const int* __restrict__ tstart,
                                             const int* __restrict__ tcnt,
                                             const unsigned short* __restrict__ csr,
                                             const unsigned short* __restrict__ h,
                                             float* __restrict__ out) {
    int w = threadIdx.x >> 6;
    int lane = threadIdx.x & 63;
    int c = blockIdx.x * 4 + w;
    if (c >= NTGT) return;

    int n = tcnt[c];
    int s0 = tstart[c];
    int q = lane >> 4;      // quarter: which edge of the group of 4
    int ql = lane & 15;     // covers cols 8*ql .. 8*ql+7

    float acc[8];
#pragma unroll
    for (int i = 0; i < 8; ++i) acc[i] = 0.f;

    int j = 0;
    while (j < n) {
        int nb = (n - j < 64) ? (n - j) : 64;
        int v = (lane < nb) ? (int)csr[s0 + j + lane] : 0;
        int n4 = nb & ~3;
        int kk = 0;
#pragma unroll 4
        for (; kk < n4; kk += 4) {
            int r = __shfl(v, kk + q, 64);
            uint4 d = *(const uint4*)(h + (size_t)r * DIM + ql * 8);
            acc[0] += bf2f(d.x & 0xffff); acc[1] += bf2f(d.x >> 16);
            acc[2] += bf2f(d.y & 0xffff); acc[3] += bf2f(d.y >> 16);
            acc[4] += bf2f(d.z & 0xffff); acc[5] += bf2f(d.z >> 16);
            acc[6] += bf2f(d.w & 0xffff); acc[7] += bf2f(d.w >> 16);
        }
        int rem = nb - kk;  // 0..3, wave-uniform
        if (rem) {
            // shfl executed by ALL lanes (divergent-source bpermute is UB)
            int qq = (q < rem) ? q : 0;
            int r = __shfl(v, kk + qq, 64);
            if (q < rem) {
                uint4 d = *(const uint4*)(h + (size_t)r * DIM + ql * 8);
                acc[0] += bf2f(d.x & 0xffff); acc[1] += bf2f(d.x >> 16);
                acc[2] += bf2f(d.y & 0xffff); acc[3] += bf2f(d.y >> 16);
                acc[4] += bf2f(d.z & 0xffff); acc[5] += bf2f(d.z >> 16);
                acc[6] += bf2f(d.w & 0xffff); acc[7] += bf2f(d.w >> 16);
            }
        }
        j += nb;
    }

    // combine quarters: butterfly over lane bits 4,5
#pragma unroll
    for (int i = 0; i < 8; ++i) {
        acc[i] += __shfl_xor(acc[i], 16, 64);
        acc[i] += __shfl_xor(acc[i], 32, 64);
    }

    if (q == 0) {
        float di = rsqrtf(1.0f + (float)n);
        float dd = di * di;
        uint4 dh = *(const uint4*)(h + (size_t)(NSRC + c) * DIM + ql * 8);
        float4 o0, o1;
        o0.x = fmaxf(di * acc[0] + dd * bf2f(dh.x & 0xffff), 0.f);
        o0.y = fmaxf(di * acc[1] + dd * bf2f(dh.x >> 16), 0.f);
        o0.z = fmaxf(di * acc[2] + dd * bf2f(dh.y & 0xffff), 0.f);
        o0.w = fmaxf(di * acc[3] + dd * bf2f(dh.y >> 16), 0.f);
        o1.x = fmaxf(di * acc[4] + dd * bf2f(dh.z & 0xffff), 0.f);
        o1.y = fmaxf(di * acc[5] + dd * bf2f(dh.z >> 16), 0.f);
        o1.z = fmaxf(di * acc[6] + dd * bf2f(dh.w & 0xffff), 0.f);
        o1.w = fmaxf(di * acc[7] + dd * bf2f(dh.w >> 16), 0.f);
        float* op = out + (size_t)(NSRC + c) * DIM + ql * 8;
        *(float4*)op = o0;
        *(float4*)(op + 4) = o1;
    }
}

extern "C" void kernel_launch(void* const* d_in, const int* in_sizes, int n_in,
                              void* d_out, int out_size, void* d_ws, size_t ws_size,
                              hipStream_t stream) {
    const int* ei     = (const int*)d_in[0];    // [2, E] int32
    const float* xsrc = (const float*)d_in[1];  // [NSRC, 128]
    const float* xtgt = (const float*)d_in[2];  // [NTGT, 128]
    const float* W    = (const float*)d_in[3];  // [128, 128]
    float* out = (float*)d_out;                 // [NTOT, 128]

    const int* row = ei;
    const int* col = ei + NEDGE;

    char* ws = (char*)d_ws;
    unsigned short* h  = (unsigned short*)ws;  ws += (size_t)NTOT * DIM * 2;   // 25.6 MB
    unsigned* part = (unsigned*)ws;            ws += (size_t)NBUCK * BCAP * 4; // 4.8 MB
    unsigned short* csr = (unsigned short*)ws; ws += (size_t)NBUCK * BCAP * 2; // 2.4 MB
    int* bcnt   = (int*)ws;                    ws += NBUCK * 4;
    int* tstart = (int*)ws;                    ws += NTGT * 4;
    int* tcnt   = (int*)ws;                    ws += NTGT * 4;

    hipMemsetAsync(bcnt, 0, NBUCK * sizeof(int), stream);
    k_front<<<FGRID, 256, 0, stream>>>(row, col, bcnt, part, xsrc, xtgt, W, h, out);
    k_bucket<<<NBUCK, 1024, 0, stream>>>(bcnt, part, csr, tstart, tcnt);
    k_agg<<<(NTGT + 3) / 4, 256, 0, stream>>>(tstart, tcnt, csr, h, out);
}

// Round 2
// 172.506 us; speedup vs baseline: 1.0763x; 1.0763x over previous
//
#include <hip/hip_runtime.h>
#include <hip/hip_bf16.h>
#include <math.h>

#define NSRC 50000
#define NTGT 50000
#define NTOT 100000
#define NEDGE 800000
#define DIM 128
#define WPAD 136        // Bs LDS row pitch (ushorts)

#define NBUCK 782       // buckets of 64 targets (49999>>6 = 781)
#define BCAP 1536       // max edges/bucket (mean 1024, sigma 32 -> +16 sigma)
#define EPT 8           // edges per thread in partition path
#define EPB2 2048       // edges per partition block (256 thr * 8)
#define PBLK2 391       // ceil(800000 / 2048)
#define GEMM_GRID 1563  // ceil(100000 / 64)
#define FGRID (PBLK2 + GEMM_GRID)

typedef __attribute__((ext_vector_type(8))) short short8;
typedef __attribute__((ext_vector_type(4))) float float4v;

union U8 { short8 s; uint4 u; };

__device__ __forceinline__ unsigned short f2bf(float f) {
    unsigned u = __float_as_uint(f);
    unsigned r = (u + 0x7FFFu + ((u >> 16) & 1u)) >> 16;  // RNE
    return (unsigned short)r;
}
__device__ __forceinline__ float bf2f(unsigned us) {
    return __uint_as_float(us << 16);
}
// packed RNE f32x2 -> bf16x2 (v_cvt_pk_bf16_f32)
__device__ __forceinline__ unsigned pkbf(float lo, float hi) {
    __hip_bfloat162 b = __float22bfloat162_rn(make_float2(lo, hi));
    return *(unsigned*)&b;
}

// ---------------- prep: W -> Wt (bf16, transposed) + zero bcnt ------------
__global__ void k_prep(const float* __restrict__ W, unsigned short* __restrict__ Wt,
                       int* __restrict__ bcnt) {
    int i = blockIdx.x * blockDim.x + threadIdx.x;
    if (i < NBUCK) bcnt[i] = 0;
    if (i < DIM * DIM) {
        int k = i >> 7, n = i & 127;
        Wt[n * DIM + k] = f2bf(W[i]);
    }
}

// ---------------- fused: edge partition (blocks 0..390) + GEMM (rest) -----
// partition: packed entry row(16b) | c_local(6b in bits 16..21)
// gemm: h = x @ W via bf16 MFMA (operand-swapped); coalesced Wt LDS fill
__global__ __launch_bounds__(256) void k_front(const int* __restrict__ row,
                                               const int* __restrict__ col,
                                               int* __restrict__ bcnt,
                                               unsigned* __restrict__ part,
                                               const float* __restrict__ xsrc,
                                               const float* __restrict__ xtgt,
                                               const unsigned short* __restrict__ Wt,
                                               unsigned short* __restrict__ h,
                                               float* __restrict__ out) {
    __shared__ union SM {
        struct { int hist[NBUCK]; int runbase[NBUCK]; int cur[NBUCK]; } p;
        unsigned short Bs[128 * WPAD];  // 34 KB -> 4 blocks/CU
    } sm;

    const int tid = threadIdx.x;

    if (blockIdx.x < PBLK2) {
        // ---------------- partition path ----------------
        for (int i = tid; i < NBUCK; i += 256) sm.p.hist[i] = 0;
        __syncthreads();

        int e0 = blockIdx.x * EPB2 + tid * EPT;
        bool valid = (e0 + EPT <= NEDGE);  // NEDGE%8==0 -> all-or-nothing
        int c[EPT], r[EPT];
        if (valid) {
            *(int4*)&c[0] = *(const int4*)(col + e0);
            *(int4*)&c[4] = *(const int4*)(col + e0 + 4);
            *(int4*)&r[0] = *(const int4*)(row + e0);
            *(int4*)&r[4] = *(const int4*)(row + e0 + 4);
#pragma unroll
            for (int i = 0; i < EPT; ++i) atomicAdd(&sm.p.hist[c[i] >> 6], 1);
        }
        __syncthreads();
        for (int i = tid; i < NBUCK; i += 256) {
            sm.p.runbase[i] = atomicAdd(&bcnt[i], sm.p.hist[i]);  // reserve run
            sm.p.cur[i] = 0;
        }
        __syncthreads();
        if (valid) {
#pragma unroll
            for (int i = 0; i < EPT; ++i) {
                int q = c[i] >> 6;
                int pos = sm.p.runbase[q] + atomicAdd(&sm.p.cur[q], 1);
                part[q * BCAP + pos] = (unsigned)r[i] | ((unsigned)(c[i] & 63) << 16);
            }
        }
        return;
    }

    // ---------------- gemm path ----------------
    const int gb = blockIdx.x - PBLK2;

    // coalesced Wt (bf16, pre-transposed) -> LDS, uint4 copies, no conflicts
    for (int idx = tid; idx < 2048; idx += 256) {
        int n = idx >> 4, c8 = idx & 15;
        *(uint4*)&sm.Bs[n * WPAD + c8 * 8] = *(const uint4*)(Wt + n * DIM + c8 * 8);
    }

    const int wave = tid >> 6, lane = tid & 63;
    const int nl = lane & 15, quad = lane >> 4;

    // prefetch x fragments (issued before the Bs barrier)
    int node = gb * 64 + wave * 16 + nl;
    int mc = (node < NTOT) ? node : (NTOT - 1);  // clamp tail loads
    const float* xrow = (mc < NSRC) ? (xsrc + (size_t)mc * DIM)
                                    : (xtgt + (size_t)(mc - NSRC) * DIM);
    float4 a[8];
#pragma unroll
    for (int s = 0; s < 4; ++s) {
        a[2 * s]     = *(const float4*)(xrow + s * 32 + quad * 8);
        a[2 * s + 1] = *(const float4*)(xrow + s * 32 + quad * 8 + 4);
    }
    __syncthreads();  // Bs ready

    float4v acc[8];
#pragma unroll
    for (int t = 0; t < 8; ++t) acc[t] = (float4v){0.f, 0.f, 0.f, 0.f};

#pragma unroll
    for (int s = 0; s < 4; ++s) {
        U8 af;
        af.u.x = pkbf(a[2 * s].x, a[2 * s].y);
        af.u.y = pkbf(a[2 * s].z, a[2 * s].w);
        af.u.z = pkbf(a[2 * s + 1].x, a[2 * s + 1].y);
        af.u.w = pkbf(a[2 * s + 1].z, a[2 * s + 1].w);
#pragma unroll
        for (int t = 0; t < 8; ++t) {
            short8 bf = *(const short8*)&sm.Bs[(t * 16 + nl) * WPAD + s * 32 + quad * 8];
            // A = W^T tile (features as M), B = x tile (nodes as N)
            acc[t] = __builtin_amdgcn_mfma_f32_16x16x32_bf16(bf, af.s, acc[t], 0, 0, 0);
        }
    }

    if (node < NTOT) {
        // lane owns node `node`, features t*16 + quad*4 .. +3
        unsigned short* hp = h + (size_t)node * DIM + quad * 4;
        float* op = out + (size_t)node * DIM + quad * 4;
        bool isrc = (node < NSRC);
#pragma unroll
        for (int t = 0; t < 8; ++t) {
            uint2 p;
            p.x = pkbf(acc[t][0], acc[t][1]);
            p.y = pkbf(acc[t][2], acc[t][3]);
            *(uint2*)(hp + t * 16) = p;
            if (isrc) {  // source nodes: deg=1 -> out = relu(h), fp32 acc
                float4 o;
                o.x = fmaxf(acc[t][0], 0.f);
                o.y = fmaxf(acc[t][1], 0.f);
                o.z = fmaxf(acc[t][2], 0.f);
                o.w = fmaxf(acc[t][3], 0.f);
                *(float4*)(op + t * 16) = o;
            }
        }
    }
}

// ---------------- per-bucket local sort -> csr (ushort) + tstart/tcnt -----
// 64-target buckets: 782 blocks x 256 thr -> ~3 blocks/CU co-resident
__global__ __launch_bounds__(256) void k_bucket(const int* __restrict__ bcnt,
                                                const unsigned* __restrict__ part,
                                                unsigned short* __restrict__ csr,
                                                int* __restrict__ tstart,
                                                int* __restrict__ tcnt) {
    __shared__ unsigned ebuf[BCAP];
    __shared__ unsigned short srt[BCAP];
    __shared__ int hist[64], bufA[64], bufB[64], cur[64];

    int q = blockIdx.x, tid = threadIdx.x;
    int n = bcnt[q];
    int base = q * BCAP;

    if (tid < 64) hist[tid] = 0;
    __syncthreads();
    for (int i = tid; i < n; i += 256) {
        unsigned p = part[base + i];
        ebuf[i] = p;
        atomicAdd(&hist[p >> 16], 1);
    }
    __syncthreads();

    // exclusive scan of hist[64] (first 64 threads, double-buffered)
    if (tid < 64) bufA[tid] = hist[tid];
    int* src = bufA; int* dst = bufB;
    for (int d = 1; d < 64; d <<= 1) {
        __syncthreads();
        if (tid < 64) dst[tid] = src[tid] + ((tid >= d) ? src[tid - d] : 0);
        int* t = src; src = dst; dst = t;
    }
    __syncthreads();
    if (tid < 64) {
        int excl = src[tid] - hist[tid];
        cur[tid] = excl;
        int c = q * 64 + tid;
        if (c < NTGT) {
            tstart[c] = base + excl;
            tcnt[c] = hist[tid];
        }
    }
    __syncthreads();

    for (int i = tid; i < n; i += 256) {
        unsigned p = ebuf[i];
        int pos = atomicAdd(&cur[p >> 16], 1);
        srt[pos] = (unsigned short)(p & 0xffffu);
    }
    __syncthreads();
    // coalesced writeout, 2 ushorts per store (base is 4B-aligned: BCAP even)
    int m = (n + 1) >> 1;
    unsigned* dst32 = (unsigned*)(csr + base);
    for (int i = tid; i < m; i += 256) dst32[i] = ((unsigned*)srt)[i];
}

// ---------------- per-target gather-reduce (bf16 h, 4 edges/iter) ---------
// one wave per target; quarter-wave (16 lanes) per edge, uint4 (8 bf16)/lane
__global__ __launch_bounds__(256) void k_agg(const int* __restrict__ tstart,
                                             const int* __restrict__ tcnt,
                                             const unsigned short* __restrict__ csr,
                                             const unsigned short* __restrict__ h,
                                             float* __restrict__ out) {
    int w = threadIdx.x >> 6;
    int lane = threadIdx.x & 63;
    int c = blockIdx.x * 4 + w;
    if (c >= NTGT) return;

    int n = tcnt[c];
    int s0 = tstart[c];
    int q = lane >> 4;      // quarter: which edge of the group of 4
    int ql = lane & 15;     // covers cols 8*ql .. 8*ql+7

    float acc[8];
#pragma unroll
    for (int i = 0; i < 8; ++i) acc[i] = 0.f;

    int j = 0;
    while (j < n) {
        int nb = (n - j < 64) ? (n - j) : 64;
        int v = (lane < nb) ? (int)csr[s0 + j + lane] : 0;
        int n4 = nb & ~3;
        int kk = 0;
#pragma unroll 4
        for (; kk < n4; kk += 4) {
            int r = __shfl(v, kk + q, 64);
            uint4 d = *(const uint4*)(h + (size_t)r * DIM + ql * 8);
            acc[0] += bf2f(d.x & 0xffff); acc[1] += bf2f(d.x >> 16);
            acc[2] += bf2f(d.y & 0xffff); acc[3] += bf2f(d.y >> 16);
            acc[4] += bf2f(d.z & 0xffff); acc[5] += bf2f(d.z >> 16);
            acc[6] += bf2f(d.w & 0xffff); acc[7] += bf2f(d.w >> 16);
        }
        int rem = nb - kk;  // 0..3, wave-uniform
        if (rem) {
            // shfl executed by ALL lanes (divergent-source bpermute is UB)
            int qq = (q < rem) ? q : 0;
            int r = __shfl(v, kk + qq, 64);
            if (q < rem) {
                uint4 d = *(const uint4*)(h + (size_t)r * DIM + ql * 8);
                acc[0] += bf2f(d.x & 0xffff); acc[1] += bf2f(d.x >> 16);
                acc[2] += bf2f(d.y & 0xffff); acc[3] += bf2f(d.y >> 16);
                acc[4] += bf2f(d.z & 0xffff); acc[5] += bf2f(d.z >> 16);
                acc[6] += bf2f(d.w & 0xffff); acc[7] += bf2f(d.w >> 16);
            }
        }
        j += nb;
    }

    // combine quarters: butterfly over lane bits 4,5
#pragma unroll
    for (int i = 0; i < 8; ++i) {
        acc[i] += __shfl_xor(acc[i], 16, 64);
        acc[i] += __shfl_xor(acc[i], 32, 64);
    }

    if (q == 0) {
        float di = rsqrtf(1.0f + (float)n);
        float dd = di * di;
        uint4 dh = *(const uint4*)(h + (size_t)(NSRC + c) * DIM + ql * 8);
        float4 o0, o1;
        o0.x = fmaxf(di * acc[0] + dd * bf2f(dh.x & 0xffff), 0.f);
        o0.y = fmaxf(di * acc[1] + dd * bf2f(dh.x >> 16), 0.f);
        o0.z = fmaxf(di * acc[2] + dd * bf2f(dh.y & 0xffff), 0.f);
        o0.w = fmaxf(di * acc[3] + dd * bf2f(dh.y >> 16), 0.f);
        o1.x = fmaxf(di * acc[4] + dd * bf2f(dh.z & 0xffff), 0.f);
        o1.y = fmaxf(di * acc[5] + dd * bf2f(dh.z >> 16), 0.f);
        o1.z = fmaxf(di * acc[6] + dd * bf2f(dh.w & 0xffff), 0.f);
        o1.w = fmaxf(di * acc[7] + dd * bf2f(dh.w >> 16), 0.f);
        float* op = out + (size_t)(NSRC + c) * DIM + ql * 8;
        *(float4*)op = o0;
        *(float4*)(op + 4) = o1;
    }
}

extern "C" void kernel_launch(void* const* d_in, const int* in_sizes, int n_in,
                              void* d_out, int out_size, void* d_ws, size_t ws_size,
                              hipStream_t stream) {
    const int* ei     = (const int*)d_in[0];    // [2, E] int32
    const float* xsrc = (const float*)d_in[1];  // [NSRC, 128]
    const float* xtgt = (const float*)d_in[2];  // [NTGT, 128]
    const float* W    = (const float*)d_in[3];  // [128, 128]
    float* out = (float*)d_out;                 // [NTOT, 128]

    const int* row = ei;
    const int* col = ei + NEDGE;

    char* ws = (char*)d_ws;
    unsigned short* h  = (unsigned short*)ws;  ws += (size_t)NTOT * DIM * 2;   // 25.6 MB
    unsigned short* Wt = (unsigned short*)ws;  ws += DIM * DIM * 2;            // 32 KB
    unsigned* part = (unsigned*)ws;            ws += (size_t)NBUCK * BCAP * 4; // 4.8 MB
    unsigned short* csr = (unsigned short*)ws; ws += (size_t)NBUCK * BCAP * 2; // 2.4 MB
    int* bcnt   = (int*)ws;                    ws += NBUCK * 4;
    int* tstart = (int*)ws;                    ws += NTGT * 4;
    int* tcnt   = (int*)ws;                    ws += NTGT * 4;

    k_prep<<<(DIM * DIM + 255) / 256, 256, 0, stream>>>(W, Wt, bcnt);
    k_front<<<FGRID, 256, 0, stream>>>(row, col, bcnt, part, xsrc, xtgt, Wt, h, out);
    k_bucket<<<NBUCK, 256, 0, stream>>>(bcnt, part, csr, tstart, tcnt);
    k_agg<<<(NTGT + 3) / 4, 256, 0, stream>>>(tstart, tcnt, csr, h, out);
}

// Round 3
// 166.930 us; speedup vs baseline: 1.1122x; 1.0334x over previous
//
#include <hip/hip_runtime.h>
#include <hip/hip_bf16.h>
#include <math.h>

#define NSRC 50000
#define NTGT 50000
#define NTOT 100000
#define NEDGE 800000
#define DIM 128

#define NBUCK 782       // buckets of 64 targets (49999>>6 = 781)
#define BCAP 1536       // max edges/bucket (mean 1024, sigma 32 -> +16 sigma)
#define BPAD 16         // bcnt stride (ints): one 64B line per bucket counter
#define EPT 8           // edges per thread in partition path
#define EPB2 2048       // edges per partition block (256 thr * 8)
#define PBLK2 391       // ceil(800000 / 2048)
#define GEMM_GRID 1563  // ceil(100000 / 64)
#define FGRID (PBLK2 + GEMM_GRID)  // 1954; partition blocks at bid%5==0

typedef __attribute__((ext_vector_type(8))) short short8;
typedef __attribute__((ext_vector_type(4))) float float4v;

union U8 { short8 s; uint4 u; };

__device__ __forceinline__ unsigned short f2bf(float f) {
    unsigned u = __float_as_uint(f);
    unsigned r = (u + 0x7FFFu + ((u >> 16) & 1u)) >> 16;  // RNE
    return (unsigned short)r;
}
__device__ __forceinline__ float bf2f(unsigned us) {
    return __uint_as_float(us << 16);
}
// packed RNE f32x2 -> bf16x2 (v_cvt_pk_bf16_f32)
__device__ __forceinline__ unsigned pkbf(float lo, float hi) {
    __hip_bfloat162 b = __float22bfloat162_rn(make_float2(lo, hi));
    return *(unsigned*)&b;
}

// ---------------- prep: W -> Wt (bf16, MFMA-fragment order) + zero bcnt ---
// Wt linear idx = ((t*4+s)*64 + lane)*8 + j  ->  W[(s*32+qd*8+j)][t*16+nl]
// so the GEMM LDS fill is a straight copy and each wave's ds_read_b128 is
// 1024 contiguous bytes (conflict-free).
__global__ __launch_bounds__(256) void k_prep(const float* __restrict__ W,
                                              unsigned short* __restrict__ Wt,
                                              int* __restrict__ bcnt) {
    int i = blockIdx.x * 256 + threadIdx.x;  // grid = 64 blocks -> i < 16384
    if (i < NBUCK * BPAD) bcnt[i] = 0;
    int j = i & 7, lane = (i >> 3) & 63, ts = i >> 9;
    int t = ts >> 2, s = ts & 3;
    int nl = lane & 15, qd = lane >> 4;
    Wt[i] = f2bf(W[(s * 32 + qd * 8 + j) * DIM + (t * 16 + nl)]);
}

// ---------------- fused: edge partition (every 5th block) + GEMM ----------
__global__ __launch_bounds__(256) void k_front(const int* __restrict__ row,
                                               const int* __restrict__ col,
                                               int* __restrict__ bcnt,
                                               unsigned* __restrict__ part,
                                               const float* __restrict__ xsrc,
                                               const float* __restrict__ xtgt,
                                               const unsigned short* __restrict__ Wt,
                                               unsigned short* __restrict__ h,
                                               float* __restrict__ out) {
    __shared__ union SM {
        struct { int hist[NBUCK]; int runbase[NBUCK]; int cur[NBUCK]; } p;
        unsigned short Bs[DIM * DIM];  // 32 KB
    } sm;

    const int tid = threadIdx.x;
    const int bid = blockIdx.x;

    if (bid % 5 == 0) {
        // ---------------- partition path ----------------
        for (int i = tid; i < NBUCK; i += 256) sm.p.hist[i] = 0;
        __syncthreads();

        int e0 = (bid / 5) * EPB2 + tid * EPT;
        bool valid = (e0 + EPT <= NEDGE);  // NEDGE%8==0 -> all-or-nothing
        int c[EPT], r[EPT];
        if (valid) {
            *(int4*)&c[0] = *(const int4*)(col + e0);
            *(int4*)&c[4] = *(const int4*)(col + e0 + 4);
            *(int4*)&r[0] = *(const int4*)(row + e0);
            *(int4*)&r[4] = *(const int4*)(row + e0 + 4);
#pragma unroll
            for (int i = 0; i < EPT; ++i) atomicAdd(&sm.p.hist[c[i] >> 6], 1);
        }
        __syncthreads();
        for (int i = tid; i < NBUCK; i += 256) {
            sm.p.runbase[i] = atomicAdd(&bcnt[i * BPAD], sm.p.hist[i]);  // reserve run
            sm.p.cur[i] = 0;
        }
        __syncthreads();
        if (valid) {
#pragma unroll
            for (int i = 0; i < EPT; ++i) {
                int q = c[i] >> 6;
                int pos = sm.p.runbase[q] + atomicAdd(&sm.p.cur[q], 1);
                part[q * BCAP + pos] = (unsigned)r[i] | ((unsigned)(c[i] & 63) << 16);
            }
        }
        return;
    }

    // ---------------- gemm path ----------------
    const int gb = bid - bid / 5 - 1;  // 0..GEMM_GRID-1

    // Wt is already fragment-ordered: straight 32 KB copy, conflict-free
    for (int idx = tid; idx < 2048; idx += 256)
        ((uint4*)sm.Bs)[idx] = ((const uint4*)Wt)[idx];

    const int wave = tid >> 6, lane = tid & 63;
    const int nl = lane & 15, quad = lane >> 4;

    // prefetch x fragments (issued before the Bs barrier)
    int node = gb * 64 + wave * 16 + nl;
    int mc = (node < NTOT) ? node : (NTOT - 1);  // clamp tail loads
    const float* xrow = (mc < NSRC) ? (xsrc + (size_t)mc * DIM)
                                    : (xtgt + (size_t)(mc - NSRC) * DIM);
    float4 a[8];
#pragma unroll
    for (int s = 0; s < 4; ++s) {
        a[2 * s]     = *(const float4*)(xrow + s * 32 + quad * 8);
        a[2 * s + 1] = *(const float4*)(xrow + s * 32 + quad * 8 + 4);
    }
    __syncthreads();  // Bs ready

    float4v acc[8];
#pragma unroll
    for (int t = 0; t < 8; ++t) acc[t] = (float4v){0.f, 0.f, 0.f, 0.f};

#pragma unroll
    for (int s = 0; s < 4; ++s) {
        U8 af;
        af.u.x = pkbf(a[2 * s].x, a[2 * s].y);
        af.u.y = pkbf(a[2 * s].z, a[2 * s].w);
        af.u.z = pkbf(a[2 * s + 1].x, a[2 * s + 1].y);
        af.u.w = pkbf(a[2 * s + 1].z, a[2 * s + 1].w);
#pragma unroll
        for (int t = 0; t < 8; ++t) {
            // fragment-ordered: wave reads 1024 contiguous bytes
            short8 bf = *(const short8*)&sm.Bs[((t * 4 + s) * 64 + lane) * 8];
            // A = W^T tile (features as M), B = x tile (nodes as N)
            acc[t] = __builtin_amdgcn_mfma_f32_16x16x32_bf16(bf, af.s, acc[t], 0, 0, 0);
        }
    }

    if (node < NTOT) {
        // lane owns node `node`, features t*16 + quad*4 .. +3
        unsigned short* hp = h + (size_t)node * DIM + quad * 4;
        float* op = out + (size_t)node * DIM + quad * 4;
        bool isrc = (node < NSRC);
#pragma unroll
        for (int t = 0; t < 8; ++t) {
            uint2 p;
            p.x = pkbf(acc[t][0], acc[t][1]);
            p.y = pkbf(acc[t][2], acc[t][3]);
            *(uint2*)(hp + t * 16) = p;
            if (isrc) {  // source nodes: deg=1 -> out = relu(h), fp32 acc
                float4 o;
                o.x = fmaxf(acc[t][0], 0.f);
                o.y = fmaxf(acc[t][1], 0.f);
                o.z = fmaxf(acc[t][2], 0.f);
                o.w = fmaxf(acc[t][3], 0.f);
                *(float4*)(op + t * 16) = o;
            }
        }
    }
}

// ---------------- fused: per-bucket sort (LDS) + gather-reduce ------------
// replaces k_bucket + k_agg: no csr/tstart/tcnt global round-trip.
// sort: hist -> scan -> scatter into srt[] (LDS). reduce: wave w handles
// targets w*16..w*16+15; quarter-wave (16 lanes) per edge; edge ids read
// from LDS (same-address broadcast within quad, conflict-free).
__global__ __launch_bounds__(256) void k_back(const int* __restrict__ bcnt,
                                              const unsigned* __restrict__ part,
                                              const unsigned short* __restrict__ h,
                                              float* __restrict__ out) {
    __shared__ unsigned ebuf[BCAP];       // 6 KB
    __shared__ unsigned short srt[BCAP];  // 3 KB
    __shared__ int hist[64], bufA[64], bufB[64], cur[64], st[64];

    int q = blockIdx.x, tid = threadIdx.x;
    int n = bcnt[q * BPAD];
    int base = q * BCAP;

    if (tid < 64) hist[tid] = 0;
    __syncthreads();
    for (int i = tid; i < n; i += 256) {
        unsigned p = part[base + i];
        ebuf[i] = p;
        atomicAdd(&hist[p >> 16], 1);
    }
    __syncthreads();

    // exclusive scan of hist[64] (first 64 threads, double-buffered)
    if (tid < 64) bufA[tid] = hist[tid];
    int* src = bufA; int* dst = bufB;
    for (int d = 1; d < 64; d <<= 1) {
        __syncthreads();
        if (tid < 64) dst[tid] = src[tid] + ((tid >= d) ? src[tid - d] : 0);
        int* tp = src; src = dst; dst = tp;
    }
    __syncthreads();
    if (tid < 64) {
        int excl = src[tid] - hist[tid];
        cur[tid] = excl;
        st[tid] = excl;
    }
    __syncthreads();
    for (int i = tid; i < n; i += 256) {
        unsigned p = ebuf[i];
        int pos = atomicAdd(&cur[p >> 16], 1);
        srt[pos] = (unsigned short)(p & 0xffffu);
    }
    __syncthreads();

    // ---------------- reduce ----------------
    int w = tid >> 6, lane = tid & 63;
    int qd = lane >> 4, ql = lane & 15;  // quad owns one edge; 16 lanes x 16B

    for (int t = 0; t < 16; ++t) {
        int cl = w * 16 + t;
        int c = q * 64 + cl;
        if (c >= NTGT) break;  // wave-uniform
        int nn = hist[cl];
        int s0 = st[cl];

        float acc[8];
#pragma unroll
        for (int i = 0; i < 8; ++i) acc[i] = 0.f;

        int kk = 0;
#pragma unroll 4
        for (; kk + 4 <= nn; kk += 4) {
            int r = (int)srt[s0 + kk + qd];
            uint4 d = *(const uint4*)(h + (size_t)r * DIM + ql * 8);
            acc[0] += bf2f(d.x & 0xffff); acc[1] += bf2f(d.x >> 16);
            acc[2] += bf2f(d.y & 0xffff); acc[3] += bf2f(d.y >> 16);
            acc[4] += bf2f(d.z & 0xffff); acc[5] += bf2f(d.z >> 16);
            acc[6] += bf2f(d.w & 0xffff); acc[7] += bf2f(d.w >> 16);
        }
        if (qd < nn - kk) {  // remainder 0..3
            int r = (int)srt[s0 + kk + qd];
            uint4 d = *(const uint4*)(h + (size_t)r * DIM + ql * 8);
            acc[0] += bf2f(d.x & 0xffff); acc[1] += bf2f(d.x >> 16);
            acc[2] += bf2f(d.y & 0xffff); acc[3] += bf2f(d.y >> 16);
            acc[4] += bf2f(d.z & 0xffff); acc[5] += bf2f(d.z >> 16);
            acc[6] += bf2f(d.w & 0xffff); acc[7] += bf2f(d.w >> 16);
        }

        // combine quarters: butterfly over lane bits 4,5
#pragma unroll
        for (int i = 0; i < 8; ++i) {
            acc[i] += __shfl_xor(acc[i], 16, 64);
            acc[i] += __shfl_xor(acc[i], 32, 64);
        }

        if (qd == 0) {
            float di = rsqrtf(1.0f + (float)nn);
            float dd = di * di;
            uint4 dh = *(const uint4*)(h + (size_t)(NSRC + c) * DIM + ql * 8);
            float4 o0, o1;
            o0.x = fmaxf(di * acc[0] + dd * bf2f(dh.x & 0xffff), 0.f);
            o0.y = fmaxf(di * acc[1] + dd * bf2f(dh.x >> 16), 0.f);
            o0.z = fmaxf(di * acc[2] + dd * bf2f(dh.y & 0xffff), 0.f);
            o0.w = fmaxf(di * acc[3] + dd * bf2f(dh.y >> 16), 0.f);
            o1.x = fmaxf(di * acc[4] + dd * bf2f(dh.z & 0xffff), 0.f);
            o1.y = fmaxf(di * acc[5] + dd * bf2f(dh.z >> 16), 0.f);
            o1.z = fmaxf(di * acc[6] + dd * bf2f(dh.w & 0xffff), 0.f);
            o1.w = fmaxf(di * acc[7] + dd * bf2f(dh.w >> 16), 0.f);
            float* op = out + (size_t)(NSRC + c) * DIM + ql * 8;
            *(float4*)op = o0;
            *(float4*)(op + 4) = o1;
        }
    }
}

extern "C" void kernel_launch(void* const* d_in, const int* in_sizes, int n_in,
                              void* d_out, int out_size, void* d_ws, size_t ws_size,
                              hipStream_t stream) {
    const int* ei     = (const int*)d_in[0];    // [2, E] int32
    const float* xsrc = (const float*)d_in[1];  // [NSRC, 128]
    const float* xtgt = (const float*)d_in[2];  // [NTGT, 128]
    const float* W    = (const float*)d_in[3];  // [128, 128]
    float* out = (float*)d_out;                 // [NTOT, 128]

    const int* row = ei;
    const int* col = ei + NEDGE;

    char* ws = (char*)d_ws;
    unsigned short* h  = (unsigned short*)ws;  ws += (size_t)NTOT * DIM * 2;   // 25.6 MB
    unsigned short* Wt = (unsigned short*)ws;  ws += DIM * DIM * 2;            // 32 KB
    unsigned* part = (unsigned*)ws;            ws += (size_t)NBUCK * BCAP * 4; // 4.8 MB
    int* bcnt = (int*)ws;                      ws += NBUCK * BPAD * 4;         // 50 KB

    k_prep<<<64, 256, 0, stream>>>(W, Wt, bcnt);
    k_front<<<FGRID, 256, 0, stream>>>(row, col, bcnt, part, xsrc, xtgt, Wt, h, out);
    k_back<<<NBUCK, 256, 0, stream>>>(bcnt, part, h, out);
}

// Round 4
// 163.888 us; speedup vs baseline: 1.1328x; 1.0186x over previous
//
#include <hip/hip_runtime.h>
#include <hip/hip_bf16.h>
#include <math.h>

#define NSRC 50000
#define NTGT 50000
#define NTOT 100000
#define NEDGE 800000
#define DIM 128

#define NBUCK 782       // buckets of 64 targets (49999>>6 = 781)
#define BCAP 1536       // max edges/bucket (mean 1024, sigma 32 -> +16 sigma)
#define BPAD 16         // bcnt stride (ints): one 64B line per bucket counter
#define BLK 512         // 8 waves per block
#define EPT 4           // edges per thread in partition path (512*4 = 2048)
#define EPB2 2048       // edges per partition block
#define PBLK2 391       // ceil(800000 / 2048)
#define GEMM_GRID 782   // ceil(100000 / 128) : 128 nodes per gemm block
#define FGRID 1173      // 391 partition (bid%3==0) + 782 gemm

typedef __attribute__((ext_vector_type(8))) short short8;
typedef __attribute__((ext_vector_type(4))) float float4v;

union U8 { short8 s; uint4 u; };

__device__ __forceinline__ unsigned short f2bf(float f) {
    unsigned u = __float_as_uint(f);
    unsigned r = (u + 0x7FFFu + ((u >> 16) & 1u)) >> 16;  // RNE
    return (unsigned short)r;
}
__device__ __forceinline__ float bf2f(unsigned us) {
    return __uint_as_float(us << 16);
}
// packed RNE f32x2 -> bf16x2 (v_cvt_pk_bf16_f32)
__device__ __forceinline__ unsigned pkbf(float lo, float hi) {
    __hip_bfloat162 b = __float22bfloat162_rn(make_float2(lo, hi));
    return *(unsigned*)&b;
}

// ---------------- prep: W -> Wt (bf16, MFMA-fragment order) + zero bcnt ---
// Wt linear idx = ((t*4+s)*64 + lane)*8 + j  ->  W[(s*32+qd*8+j)][t*16+nl]
// so the GEMM LDS fill is a straight copy and each wave's ds_read_b128 is
// 1024 contiguous bytes (conflict-free).
__global__ __launch_bounds__(256) void k_prep(const float* __restrict__ W,
                                              unsigned short* __restrict__ Wt,
                                              int* __restrict__ bcnt) {
    int i = blockIdx.x * 256 + threadIdx.x;  // grid = 64 blocks -> i < 16384
    if (i < NBUCK * BPAD) bcnt[i] = 0;
    int j = i & 7, lane = (i >> 3) & 63, ts = i >> 9;
    int t = ts >> 2, s = ts & 3;
    int nl = lane & 15, qd = lane >> 4;
    Wt[i] = f2bf(W[(s * 32 + qd * 8 + j) * DIM + (t * 16 + nl)]);
}

// ---------------- fused: edge partition (every 3rd block) + GEMM ----------
// 512 threads: partition path = 2048 edges (EPT 4); gemm path = 8 waves x
// 16 nodes = 128 nodes per block, one 32KB Bs fill per 128 nodes.
__global__ __launch_bounds__(BLK) void k_front(const int* __restrict__ row,
                                               const int* __restrict__ col,
                                               int* __restrict__ bcnt,
                                               unsigned* __restrict__ part,
                                               const float* __restrict__ xsrc,
                                               const float* __restrict__ xtgt,
                                               const unsigned short* __restrict__ Wt,
                                               unsigned short* __restrict__ h,
                                               float* __restrict__ out) {
    __shared__ union SM {
        struct { int hist[NBUCK]; int runbase[NBUCK]; int cur[NBUCK]; } p;
        unsigned short Bs[DIM * DIM];  // 32 KB -> 4 blocks/CU, 32 waves/CU
    } sm;

    const int tid = threadIdx.x;
    const int bid = blockIdx.x;

    if (bid % 3 == 0) {
        // ---------------- partition path ----------------
        for (int i = tid; i < NBUCK; i += BLK) sm.p.hist[i] = 0;
        __syncthreads();

        int e0 = (bid / 3) * EPB2 + tid * EPT;
        bool valid = (e0 + EPT <= NEDGE);  // NEDGE%4==0 -> all-or-nothing
        int c[EPT], r[EPT];
        if (valid) {
            *(int4*)&c[0] = *(const int4*)(col + e0);
            *(int4*)&r[0] = *(const int4*)(row + e0);
#pragma unroll
            for (int i = 0; i < EPT; ++i) atomicAdd(&sm.p.hist[c[i] >> 6], 1);
        }
        __syncthreads();
        for (int i = tid; i < NBUCK; i += BLK) {
            sm.p.runbase[i] = atomicAdd(&bcnt[i * BPAD], sm.p.hist[i]);  // reserve run
            sm.p.cur[i] = 0;
        }
        __syncthreads();
        if (valid) {
#pragma unroll
            for (int i = 0; i < EPT; ++i) {
                int q = c[i] >> 6;
                int pos = sm.p.runbase[q] + atomicAdd(&sm.p.cur[q], 1);
                part[q * BCAP + pos] = (unsigned)r[i] | ((unsigned)(c[i] & 63) << 16);
            }
        }
        return;
    }

    // ---------------- gemm path ----------------
    const int gb = bid - bid / 3 - 1;  // 0..GEMM_GRID-1

    // Wt is already fragment-ordered: straight 32 KB copy, conflict-free
    for (int idx = tid; idx < 2048; idx += BLK)
        ((uint4*)sm.Bs)[idx] = ((const uint4*)Wt)[idx];

    const int wave = tid >> 6, lane = tid & 63;
    const int nl = lane & 15, quad = lane >> 4;

    // prefetch x fragments (issued before the Bs barrier)
    int node = gb * 128 + wave * 16 + nl;
    int mc = (node < NTOT) ? node : (NTOT - 1);  // clamp tail loads
    const float* xrow = (mc < NSRC) ? (xsrc + (size_t)mc * DIM)
                                    : (xtgt + (size_t)(mc - NSRC) * DIM);
    float4 a[8];
#pragma unroll
    for (int s = 0; s < 4; ++s) {
        a[2 * s]     = *(const float4*)(xrow + s * 32 + quad * 8);
        a[2 * s + 1] = *(const float4*)(xrow + s * 32 + quad * 8 + 4);
    }
    __syncthreads();  // Bs ready

    float4v acc[8];
#pragma unroll
    for (int t = 0; t < 8; ++t) acc[t] = (float4v){0.f, 0.f, 0.f, 0.f};

#pragma unroll
    for (int s = 0; s < 4; ++s) {
        U8 af;
        af.u.x = pkbf(a[2 * s].x, a[2 * s].y);
        af.u.y = pkbf(a[2 * s].z, a[2 * s].w);
        af.u.z = pkbf(a[2 * s + 1].x, a[2 * s + 1].y);
        af.u.w = pkbf(a[2 * s + 1].z, a[2 * s + 1].w);
#pragma unroll
        for (int t = 0; t < 8; ++t) {
            // fragment-ordered: wave reads 1024 contiguous bytes
            short8 bf = *(const short8*)&sm.Bs[((t * 4 + s) * 64 + lane) * 8];
            // A = W^T tile (features as M), B = x tile (nodes as N)
            acc[t] = __builtin_amdgcn_mfma_f32_16x16x32_bf16(bf, af.s, acc[t], 0, 0, 0);
        }
    }

    if (node < NTOT) {
        // lane owns node `node`, features t*16 + quad*4 .. +3
        unsigned short* hp = h + (size_t)node * DIM + quad * 4;
        float* op = out + (size_t)node * DIM + quad * 4;
        bool isrc = (node < NSRC);
#pragma unroll
        for (int t = 0; t < 8; ++t) {
            uint2 p;
            p.x = pkbf(acc[t][0], acc[t][1]);
            p.y = pkbf(acc[t][2], acc[t][3]);
            *(uint2*)(hp + t * 16) = p;
            if (isrc) {  // source nodes: deg=1 -> out = relu(h), fp32 acc
                float4 o;
                o.x = fmaxf(acc[t][0], 0.f);
                o.y = fmaxf(acc[t][1], 0.f);
                o.z = fmaxf(acc[t][2], 0.f);
                o.w = fmaxf(acc[t][3], 0.f);
                *(float4*)(op + t * 16) = o;
            }
        }
    }
}

// ---------------- fused: per-bucket sort (LDS) + gather-reduce ------------
// 512 threads: 8 waves x 8 targets/wave. Sort: hist -> scan -> scatter into
// srt[] (LDS). Reduce: quarter-wave (16 lanes) per edge, uint4 per lane.
__global__ __launch_bounds__(BLK) void k_back(const int* __restrict__ bcnt,
                                              const unsigned* __restrict__ part,
                                              const unsigned short* __restrict__ h,
                                              float* __restrict__ out) {
    __shared__ unsigned ebuf[BCAP];       // 6 KB
    __shared__ unsigned short srt[BCAP];  // 3 KB
    __shared__ int hist[64], bufA[64], bufB[64], cur[64], st[64];

    int q = blockIdx.x, tid = threadIdx.x;
    int n = bcnt[q * BPAD];
    int base = q * BCAP;

    if (tid < 64) hist[tid] = 0;
    __syncthreads();
    for (int i = tid; i < n; i += BLK) {
        unsigned p = part[base + i];
        ebuf[i] = p;
        atomicAdd(&hist[p >> 16], 1);
    }
    __syncthreads();

    // exclusive scan of hist[64] (first 64 threads, double-buffered)
    if (tid < 64) bufA[tid] = hist[tid];
    int* src = bufA; int* dst = bufB;
    for (int d = 1; d < 64; d <<= 1) {
        __syncthreads();
        if (tid < 64) dst[tid] = src[tid] + ((tid >= d) ? src[tid - d] : 0);
        int* tp = src; src = dst; dst = tp;
    }
    __syncthreads();
    if (tid < 64) {
        int excl = src[tid] - hist[tid];
        cur[tid] = excl;
        st[tid] = excl;
    }
    __syncthreads();
    for (int i = tid; i < n; i += BLK) {
        unsigned p = ebuf[i];
        int pos = atomicAdd(&cur[p >> 16], 1);
        srt[pos] = (unsigned short)(p & 0xffffu);
    }
    __syncthreads();

    // ---------------- reduce ----------------
    int w = tid >> 6, lane = tid & 63;
    int qd = lane >> 4, ql = lane & 15;  // quad owns one edge; 16 lanes x 16B

    for (int t = 0; t < 8; ++t) {
        int cl = w * 8 + t;
        int c = q * 64 + cl;
        if (c >= NTGT) break;  // wave-uniform
        int nn = hist[cl];
        int s0 = st[cl];

        float acc[8];
#pragma unroll
        for (int i = 0; i < 8; ++i) acc[i] = 0.f;

        int kk = 0;
#pragma unroll 4
        for (; kk + 4 <= nn; kk += 4) {
            int r = (int)srt[s0 + kk + qd];
            uint4 d = *(const uint4*)(h + (size_t)r * DIM + ql * 8);
            acc[0] += bf2f(d.x & 0xffff); acc[1] += bf2f(d.x >> 16);
            acc[2] += bf2f(d.y & 0xffff); acc[3] += bf2f(d.y >> 16);
            acc[4] += bf2f(d.z & 0xffff); acc[5] += bf2f(d.z >> 16);
            acc[6] += bf2f(d.w & 0xffff); acc[7] += bf2f(d.w >> 16);
        }
        if (qd < nn - kk) {  // remainder 0..3
            int r = (int)srt[s0 + kk + qd];
            uint4 d = *(const uint4*)(h + (size_t)r * DIM + ql * 8);
            acc[0] += bf2f(d.x & 0xffff); acc[1] += bf2f(d.x >> 16);
            acc[2] += bf2f(d.y & 0xffff); acc[3] += bf2f(d.y >> 16);
            acc[4] += bf2f(d.z & 0xffff); acc[5] += bf2f(d.z >> 16);
            acc[6] += bf2f(d.w & 0xffff); acc[7] += bf2f(d.w >> 16);
        }

        // combine quarters: butterfly over lane bits 4,5
#pragma unroll
        for (int i = 0; i < 8; ++i) {
            acc[i] += __shfl_xor(acc[i], 16, 64);
            acc[i] += __shfl_xor(acc[i], 32, 64);
        }

        if (qd == 0) {
            float di = rsqrtf(1.0f + (float)nn);
            float dd = di * di;
            uint4 dh = *(const uint4*)(h + (size_t)(NSRC + c) * DIM + ql * 8);
            float4 o0, o1;
            o0.x = fmaxf(di * acc[0] + dd * bf2f(dh.x & 0xffff), 0.f);
            o0.y = fmaxf(di * acc[1] + dd * bf2f(dh.x >> 16), 0.f);
            o0.z = fmaxf(di * acc[2] + dd * bf2f(dh.y & 0xffff), 0.f);
            o0.w = fmaxf(di * acc[3] + dd * bf2f(dh.y >> 16), 0.f);
            o1.x = fmaxf(di * acc[4] + dd * bf2f(dh.z & 0xffff), 0.f);
            o1.y = fmaxf(di * acc[5] + dd * bf2f(dh.z >> 16), 0.f);
            o1.z = fmaxf(di * acc[6] + dd * bf2f(dh.w & 0xffff), 0.f);
            o1.w = fmaxf(di * acc[7] + dd * bf2f(dh.w >> 16), 0.f);
            float* op = out + (size_t)(NSRC + c) * DIM + ql * 8;
            *(float4*)op = o0;
            *(float4*)(op + 4) = o1;
        }
    }
}

extern "C" void kernel_launch(void* const* d_in, const int* in_sizes, int n_in,
                              void* d_out, int out_size, void* d_ws, size_t ws_size,
                              hipStream_t stream) {
    const int* ei     = (const int*)d_in[0];    // [2, E] int32
    const float* xsrc = (const float*)d_in[1];  // [NSRC, 128]
    const float* xtgt = (const float*)d_in[2];  // [NTGT, 128]
    const float* W    = (const float*)d_in[3];  // [128, 128]
    float* out = (float*)d_out;                 // [NTOT, 128]

    const int* row = ei;
    const int* col = ei + NEDGE;

    char* ws = (char*)d_ws;
    unsigned short* h  = (unsigned short*)ws;  ws += (size_t)NTOT * DIM * 2;   // 25.6 MB
    unsigned short* Wt = (unsigned short*)ws;  ws += DIM * DIM * 2;            // 32 KB
    unsigned* part = (unsigned*)ws;            ws += (size_t)NBUCK * BCAP * 4; // 4.8 MB
    int* bcnt = (int*)ws;                      ws += NBUCK * BPAD * 4;         // 50 KB

    k_prep<<<64, 256, 0, stream>>>(W, Wt, bcnt);
    k_front<<<FGRID, BLK, 0, stream>>>(row, col, bcnt, part, xsrc, xtgt, Wt, h, out);
    k_back<<<NBUCK, BLK, 0, stream>>>(bcnt, part, h, out);
}